// Round 2
// baseline (3270.509 us; speedup 1.0000x reference)
//
#include <hip/hip_runtime.h>
#include <hip/hip_bf16.h>
#include <math.h>

// Problem constants
#define B_SZ 16
#define S_LEN 729
#define EMB 1152
#define NH 16
#define DH 72
#define SCALE 0.11785113019775792f  // 72^-0.5

// ---------------------------------------------------------------------------
// Tiled fp32 GEMM with bias:  C[M,N] = A[M,K] @ W[K,N] + bias[N]
// 64x64 tile, BK=16, 256 threads, 4x4 microtile per thread.
// ---------------------------------------------------------------------------
__global__ __launch_bounds__(256) void gemm_bias_kernel(
    const float* __restrict__ A, const float* __restrict__ W,
    const float* __restrict__ bias, float* __restrict__ C,
    int M, int N, int K)
{
    __shared__ float As[16][68];   // [k][m], padded: 68*4B stride keeps 16B align + spreads banks
    __shared__ float Ws[16][64];   // [k][n]

    const int tid  = threadIdx.x;
    const int row0 = blockIdx.x * 64;
    const int col0 = blockIdx.y * 64;

    const int tr = tid >> 4;          // 0..15 -> rows tr*4..tr*4+3
    const int tc = tid & 15;          // 0..15 -> cols tc*4..tc*4+3

    // A-load mapping: each thread loads 4 consecutive k for one row
    const int lm = tid >> 2;          // 0..63 row in tile
    const int lk = (tid & 3) * 4;     // 0,4,8,12
    // W-load mapping: each thread loads 4 consecutive n for one k
    const int wk = tid >> 4;          // 0..15
    const int wn = (tid & 15) * 4;    // 0..60

    float acc[4][4];
#pragma unroll
    for (int i = 0; i < 4; ++i)
#pragma unroll
        for (int j = 0; j < 4; ++j) acc[i][j] = 0.f;

    for (int k0 = 0; k0 < K; k0 += 16) {
        // stage A tile (transposed into [k][m])
        const int arow = row0 + lm;
        float4 av = make_float4(0.f, 0.f, 0.f, 0.f);
        if (arow < M)
            av = *reinterpret_cast<const float4*>(A + (size_t)arow * K + k0 + lk);
        As[lk + 0][lm] = av.x;
        As[lk + 1][lm] = av.y;
        As[lk + 2][lm] = av.z;
        As[lk + 3][lm] = av.w;
        // stage W tile
        float4 wv = *reinterpret_cast<const float4*>(W + (size_t)(k0 + wk) * N + col0 + wn);
        *reinterpret_cast<float4*>(&Ws[wk][wn]) = wv;
        __syncthreads();

#pragma unroll
        for (int kk = 0; kk < 16; ++kk) {
            float a[4], b[4];
#pragma unroll
            for (int i = 0; i < 4; ++i) a[i] = As[kk][tr * 4 + i];
#pragma unroll
            for (int j = 0; j < 4; ++j) b[j] = Ws[kk][tc * 4 + j];
#pragma unroll
            for (int i = 0; i < 4; ++i)
#pragma unroll
                for (int j = 0; j < 4; ++j)
                    acc[i][j] = fmaf(a[i], b[j], acc[i][j]);
        }
        __syncthreads();
    }

    // epilogue: bias + store
    float bb[4];
#pragma unroll
    for (int j = 0; j < 4; ++j) bb[j] = bias[col0 + tc * 4 + j];
#pragma unroll
    for (int i = 0; i < 4; ++i) {
        const int r = row0 + tr * 4 + i;
        if (r < M) {
            float4 o;
            o.x = acc[i][0] + bb[0];
            o.y = acc[i][1] + bb[1];
            o.z = acc[i][2] + bb[2];
            o.w = acc[i][3] + bb[3];
            *reinterpret_cast<float4*>(C + (size_t)r * N + col0 + tc * 4) = o;
        }
    }
}

// ---------------------------------------------------------------------------
// Flash-style attention. q/k/v/o live in [B, S, EMB] layout where head h
// occupies columns [h*DH, (h+1)*DH). One thread per (b, h, q-row),
// online softmax over all 729 keys. K/V row loads are wave-uniform
// (whole block shares (b,h)) -> broadcast from cache.
// ---------------------------------------------------------------------------
__global__ __launch_bounds__(256) void attn_kernel(
    const float* __restrict__ q, const float* __restrict__ k,
    const float* __restrict__ v, float* __restrict__ o)
{
    const int bh = blockIdx.x;          // b*NH + h
    const int b  = bh >> 4;
    const int h  = bh & 15;
    const int qi = blockIdx.y * 256 + threadIdx.x;
    if (qi >= S_LEN) return;

    const size_t base = (size_t)b * S_LEN * EMB + (size_t)h * DH;

    // load this thread's query row (72 floats, 16B aligned)
    float qr[DH];
    const float* qrow = q + base + (size_t)qi * EMB;
#pragma unroll
    for (int d = 0; d < DH; d += 4) {
        float4 t = *reinterpret_cast<const float4*>(qrow + d);
        qr[d] = t.x; qr[d + 1] = t.y; qr[d + 2] = t.z; qr[d + 3] = t.w;
    }

    float m = -INFINITY;
    float l = 0.f;
    float acc[DH];
#pragma unroll
    for (int d = 0; d < DH; ++d) acc[d] = 0.f;

    for (int kk = 0; kk < S_LEN; ++kk) {
        const float* krow = k + base + (size_t)kk * EMB;
        float s0 = 0.f, s1 = 0.f, s2 = 0.f, s3 = 0.f;
#pragma unroll
        for (int d = 0; d < DH; d += 4) {
            float4 t = *reinterpret_cast<const float4*>(krow + d);
            s0 = fmaf(qr[d],     t.x, s0);
            s1 = fmaf(qr[d + 1], t.y, s1);
            s2 = fmaf(qr[d + 2], t.z, s2);
            s3 = fmaf(qr[d + 3], t.w, s3);
        }
        const float s = ((s0 + s1) + (s2 + s3)) * SCALE;

        const float mnew = fmaxf(m, s);
        const float corr = __expf(m - mnew);   // 0 on first iter (m = -inf)
        const float p    = __expf(s - mnew);
        l = l * corr + p;

        const float* vrow = v + base + (size_t)kk * EMB;
#pragma unroll
        for (int d = 0; d < DH; d += 4) {
            float4 t = *reinterpret_cast<const float4*>(vrow + d);
            acc[d]     = fmaf(acc[d],     corr, p * t.x);
            acc[d + 1] = fmaf(acc[d + 1], corr, p * t.y);
            acc[d + 2] = fmaf(acc[d + 2], corr, p * t.z);
            acc[d + 3] = fmaf(acc[d + 3], corr, p * t.w);
        }
        m = mnew;
    }

    const float inv = 1.f / l;
    float* orow = o + base + (size_t)qi * EMB;
#pragma unroll
    for (int d = 0; d < DH; d += 4) {
        float4 t;
        t.x = acc[d] * inv;
        t.y = acc[d + 1] * inv;
        t.z = acc[d + 2] * inv;
        t.w = acc[d + 3] * inv;
        *reinterpret_cast<float4*>(orow + d) = t;
    }
}

// ---------------------------------------------------------------------------
extern "C" void kernel_launch(void* const* d_in, const int* in_sizes, int n_in,
                              void* d_out, int out_size, void* d_ws, size_t ws_size,
                              hipStream_t stream)
{
    const float* x  = (const float*)d_in[0];
    const float* wq = (const float*)d_in[1];
    const float* bq = (const float*)d_in[2];
    const float* wk = (const float*)d_in[3];
    const float* bk = (const float*)d_in[4];
    const float* wv = (const float*)d_in[5];
    const float* bv = (const float*)d_in[6];
    const float* wo = (const float*)d_in[7];
    const float* bo = (const float*)d_in[8];
    float* out = (float*)d_out;

    const int M = B_SZ * S_LEN;   // 11664
    const int D = EMB;            // 1152

    float* ws = (float*)d_ws;
    const size_t per = (size_t)M * D;     // 13.4M floats
    float* qb = ws;
    float* kb = ws + per;
    float* vb = ws + 2 * per;
    float* ab = ws + 3 * per;

    dim3 gg((M + 63) / 64, D / 64);   // 183 x 18
    dim3 bb(256);

    gemm_bias_kernel<<<gg, bb, 0, stream>>>(x, wq, bq, qb, M, D, D);
    gemm_bias_kernel<<<gg, bb, 0, stream>>>(x, wk, bk, kb, M, D, D);
    gemm_bias_kernel<<<gg, bb, 0, stream>>>(x, wv, bv, vb, M, D, D);

    dim3 ga(B_SZ * NH, (S_LEN + 255) / 256);  // 256 x 3
    attn_kernel<<<ga, bb, 0, stream>>>(qb, kb, vb, ab);

    gemm_bias_kernel<<<gg, bb, 0, stream>>>(ab, wo, bo, out, M, D, D);
}

// Round 3
// 2615.960 us; speedup vs baseline: 1.2502x; 1.2502x over previous
//
#include <hip/hip_runtime.h>
#include <math.h>

// Problem constants
#define B_SZ 16
#define S_LEN 729
#define EMB 1152
#define NH 16
#define DH 72
#define SCALE 0.11785113019775792f  // 72^-0.5
#define M_ROWS (B_SZ * S_LEN)       // 11664

typedef __bf16 bf16x8 __attribute__((ext_vector_type(8)));
typedef float  f32x4  __attribute__((ext_vector_type(4)));

__device__ __forceinline__ unsigned short f32_bf16(float f) {
    unsigned int u = __float_as_uint(f);
    u = (u + 0x7FFFu + ((u >> 16) & 1u)) >> 16;   // RNE
    return (unsigned short)u;
}
__device__ __forceinline__ float bf16_f32(unsigned short h) {
    return __uint_as_float(((unsigned int)h) << 16);
}

// ---------------------------------------------------------------------------
// fp32 -> bf16 convert (8 elems/thread)
// ---------------------------------------------------------------------------
__global__ __launch_bounds__(256) void cvt_bf16_kernel(
    const float* __restrict__ in, unsigned short* __restrict__ out, int n8)
{
    int i = blockIdx.x * 256 + threadIdx.x;
    if (i >= n8) return;
    const float4* p = reinterpret_cast<const float4*>(in) + 2 * (size_t)i;
    float4 a = p[0], b = p[1];
    uint4 o;
    o.x = (unsigned int)f32_bf16(a.x) | ((unsigned int)f32_bf16(a.y) << 16);
    o.y = (unsigned int)f32_bf16(a.z) | ((unsigned int)f32_bf16(a.w) << 16);
    o.z = (unsigned int)f32_bf16(b.x) | ((unsigned int)f32_bf16(b.y) << 16);
    o.w = (unsigned int)f32_bf16(b.z) | ((unsigned int)f32_bf16(b.w) << 16);
    reinterpret_cast<uint4*>(out)[i] = o;
}

// fp32 -> (hi, lo) bf16 split
__global__ __launch_bounds__(256) void cvt_split_kernel(
    const float* __restrict__ in, unsigned short* __restrict__ hi,
    unsigned short* __restrict__ lo, int n8)
{
    int i = blockIdx.x * 256 + threadIdx.x;
    if (i >= n8) return;
    const float4* p = reinterpret_cast<const float4*>(in) + 2 * (size_t)i;
    float4 a = p[0], b = p[1];
    float f[8] = {a.x, a.y, a.z, a.w, b.x, b.y, b.z, b.w};
    unsigned short h[8], l[8];
#pragma unroll
    for (int j = 0; j < 8; ++j) {
        h[j] = f32_bf16(f[j]);
        l[j] = f32_bf16(f[j] - bf16_f32(h[j]));
    }
    uint4 oh, ol;
    oh.x = h[0] | ((unsigned int)h[1] << 16); oh.y = h[2] | ((unsigned int)h[3] << 16);
    oh.z = h[4] | ((unsigned int)h[5] << 16); oh.w = h[6] | ((unsigned int)h[7] << 16);
    ol.x = l[0] | ((unsigned int)l[1] << 16); ol.y = l[2] | ((unsigned int)l[3] << 16);
    ol.z = l[4] | ((unsigned int)l[5] << 16); ol.w = l[6] | ((unsigned int)l[7] << 16);
    reinterpret_cast<uint4*>(hi)[i] = oh;
    reinterpret_cast<uint4*>(lo)[i] = ol;
}

// ---------------------------------------------------------------------------
// Transpose + convert: W fp32 [K=1152][N=1152] -> Wt bf16 [N][K] (+ lo split)
// 32x32 LDS tile.
// ---------------------------------------------------------------------------
template<bool SPLIT>
__global__ __launch_bounds__(256) void tcvt_kernel(
    const float* __restrict__ W, unsigned short* __restrict__ Th,
    unsigned short* __restrict__ Tl)
{
    __shared__ float Ts[32][33];
    const int bk = blockIdx.x, bn = blockIdx.y;
    const int t = threadIdx.x;
    const int r  = t >> 3;
    const int c4 = (t & 7) * 4;
    float4 f = *reinterpret_cast<const float4*>(W + (size_t)(bk * 32 + r) * EMB + bn * 32 + c4);
    Ts[r][c4] = f.x; Ts[r][c4 + 1] = f.y; Ts[r][c4 + 2] = f.z; Ts[r][c4 + 3] = f.w;
    __syncthreads();
    // Wt[bn*32 + r][bk*32 + c4 + i] = W[bk*32 + c4 + i][bn*32 + r] = Ts[c4+i][r]
    float v[4];
#pragma unroll
    for (int i = 0; i < 4; ++i) v[i] = Ts[c4 + i][r];
    unsigned short h[4];
#pragma unroll
    for (int i = 0; i < 4; ++i) h[i] = f32_bf16(v[i]);
    uint2 oh;
    oh.x = h[0] | ((unsigned int)h[1] << 16);
    oh.y = h[2] | ((unsigned int)h[3] << 16);
    *reinterpret_cast<uint2*>(Th + (size_t)(bn * 32 + r) * EMB + bk * 32 + c4) = oh;
    if (SPLIT) {
        unsigned short l[4];
#pragma unroll
        for (int i = 0; i < 4; ++i) l[i] = f32_bf16(v[i] - bf16_f32(h[i]));
        uint2 ol;
        ol.x = l[0] | ((unsigned int)l[1] << 16);
        ol.y = l[2] | ((unsigned int)l[3] << 16);
        *reinterpret_cast<uint2*>(Tl + (size_t)(bn * 32 + r) * EMB + bk * 32 + c4) = ol;
    }
}

// ---------------------------------------------------------------------------
// bf16 MFMA GEMM:  C[M=11664][1152] = A[M][1152] @ Wt[1152][1152]^T (+ bias)
// A row-major [m][k] bf16; Wt row-major [n][k] bf16 (pre-transposed weights).
// 128x128 tile, BK=32, 256 threads = 4 waves (2x2), each wave 64x64 out
// = 4x4 grid of 16x16x32 MFMA frags. Double-buffered LDS, reg-staged.
// ---------------------------------------------------------------------------
template<bool ACCUM>
__global__ __launch_bounds__(256) void mfma_gemm_kernel(
    const unsigned short* __restrict__ A,
    const unsigned short* __restrict__ Wt,
    const float* __restrict__ bias,
    float* __restrict__ C)
{
    __shared__ __align__(16) unsigned short As[2][128 * 32];
    __shared__ __align__(16) unsigned short Ws[2][128 * 32];

    const int tid  = threadIdx.x;
    const int lane = tid & 63;
    const int wid  = tid >> 6;
    const int wr   = wid >> 1;       // 0..1
    const int wc   = wid & 1;        // 0..1
    const int row0 = blockIdx.x * 128;
    const int col0 = blockIdx.y * 128;

    // staging map: thread t covers rows {0,64}+t/4, 16B chunk t%4 of the 64B row
    const int srow = tid >> 2;       // 0..63
    const int sch  = tid & 3;        // 0..3

    f32x4 acc[4][4];
#pragma unroll
    for (int i = 0; i < 4; ++i)
#pragma unroll
        for (int j = 0; j < 4; ++j) acc[i][j] = (f32x4){0.f, 0.f, 0.f, 0.f};

    uint4 avr[2], wvr[2];

    auto loadAW = [&](int k0) {
#pragma unroll
        for (int s = 0; s < 2; ++s) {
            int ra = row0 + s * 64 + srow;
            if (ra > M_ROWS - 1) ra = M_ROWS - 1;     // clamp (values unused)
            avr[s] = *reinterpret_cast<const uint4*>(A + (size_t)ra * EMB + k0 + sch * 8);
            const int rw = col0 + s * 64 + srow;      // < 1152 always
            wvr[s] = *reinterpret_cast<const uint4*>(Wt + (size_t)rw * EMB + k0 + sch * 8);
        }
    };
    auto storeLDS = [&](int b) {
#pragma unroll
        for (int s = 0; s < 2; ++s) {
            *reinterpret_cast<uint4*>(&As[b][(s * 64 + srow) * 32 + sch * 8]) = avr[s];
            *reinterpret_cast<uint4*>(&Ws[b][(s * 64 + srow) * 32 + sch * 8]) = wvr[s];
        }
    };

    loadAW(0);
    storeLDS(0);
    __syncthreads();

    const int NK = EMB / 32;   // 36
    for (int t = 0; t < NK; ++t) {
        if (t + 1 < NK) loadAW((t + 1) * 32);
        const int b = t & 1;
        bf16x8 af[4], bfr[4];
#pragma unroll
        for (int i = 0; i < 4; ++i)
            af[i] = *reinterpret_cast<const bf16x8*>(
                &As[b][(wr * 64 + i * 16 + (lane & 15)) * 32 + (lane >> 4) * 8]);
#pragma unroll
        for (int j = 0; j < 4; ++j)
            bfr[j] = *reinterpret_cast<const bf16x8*>(
                &Ws[b][(wc * 64 + j * 16 + (lane & 15)) * 32 + (lane >> 4) * 8]);
#pragma unroll
        for (int i = 0; i < 4; ++i)
#pragma unroll
            for (int j = 0; j < 4; ++j)
                acc[i][j] = __builtin_amdgcn_mfma_f32_16x16x32_bf16(af[i], bfr[j], acc[i][j], 0, 0, 0);
        if (t + 1 < NK) storeLDS(b ^ 1);
        __syncthreads();
    }

    // epilogue: C/D layout col=lane&15, row=(lane>>4)*4+reg  [m89/m91]
    const int crow = (lane >> 4) * 4;
    const int ccol = lane & 15;
#pragma unroll
    for (int j = 0; j < 4; ++j) {
        const int cg = col0 + wc * 64 + j * 16 + ccol;
        float bj = 0.f;
        if (!ACCUM) bj = bias[cg];
#pragma unroll
        for (int i = 0; i < 4; ++i) {
            const int rbase = row0 + wr * 64 + i * 16 + crow;
#pragma unroll
            for (int r = 0; r < 4; ++r) {
                const int rg = rbase + r;
                if (rg < M_ROWS) {
                    const size_t idx = (size_t)rg * EMB + cg;
                    if (ACCUM) C[idx] += acc[i][j][r];
                    else       C[idx]  = acc[i][j][r] + bj;
                }
            }
        }
    }
}

// ---------------------------------------------------------------------------
// Flash-style attention (unchanged from verified round-2 kernel).
// ---------------------------------------------------------------------------
__global__ __launch_bounds__(256) void attn_kernel(
    const float* __restrict__ q, const float* __restrict__ k,
    const float* __restrict__ v, float* __restrict__ o)
{
    const int bh = blockIdx.x;          // b*NH + h
    const int b  = bh >> 4;
    const int h  = bh & 15;
    const int qi = blockIdx.y * 256 + threadIdx.x;
    if (qi >= S_LEN) return;

    const size_t base = (size_t)b * S_LEN * EMB + (size_t)h * DH;

    float qr[DH];
    const float* qrow = q + base + (size_t)qi * EMB;
#pragma unroll
    for (int d = 0; d < DH; d += 4) {
        float4 t = *reinterpret_cast<const float4*>(qrow + d);
        qr[d] = t.x; qr[d + 1] = t.y; qr[d + 2] = t.z; qr[d + 3] = t.w;
    }

    float m = -INFINITY;
    float l = 0.f;
    float acc[DH];
#pragma unroll
    for (int d = 0; d < DH; ++d) acc[d] = 0.f;

    for (int kk = 0; kk < S_LEN; ++kk) {
        const float* krow = k + base + (size_t)kk * EMB;
        float s0 = 0.f, s1 = 0.f, s2 = 0.f, s3 = 0.f;
#pragma unroll
        for (int d = 0; d < DH; d += 4) {
            float4 t = *reinterpret_cast<const float4*>(krow + d);
            s0 = fmaf(qr[d],     t.x, s0);
            s1 = fmaf(qr[d + 1], t.y, s1);
            s2 = fmaf(qr[d + 2], t.z, s2);
            s3 = fmaf(qr[d + 3], t.w, s3);
        }
        const float s = ((s0 + s1) + (s2 + s3)) * SCALE;

        const float mnew = fmaxf(m, s);
        const float corr = __expf(m - mnew);
        const float p    = __expf(s - mnew);
        l = l * corr + p;

        const float* vrow = v + base + (size_t)kk * EMB;
#pragma unroll
        for (int d = 0; d < DH; d += 4) {
            float4 t = *reinterpret_cast<const float4*>(vrow + d);
            acc[d]     = fmaf(acc[d],     corr, p * t.x);
            acc[d + 1] = fmaf(acc[d + 1], corr, p * t.y);
            acc[d + 2] = fmaf(acc[d + 2], corr, p * t.z);
            acc[d + 3] = fmaf(acc[d + 3], corr, p * t.w);
        }
        m = mnew;
    }

    const float inv = 1.f / l;
    float* orow = o + base + (size_t)qi * EMB;
#pragma unroll
    for (int d = 0; d < DH; d += 4) {
        float4 t;
        t.x = acc[d] * inv;
        t.y = acc[d + 1] * inv;
        t.z = acc[d + 2] * inv;
        t.w = acc[d + 3] * inv;
        *reinterpret_cast<float4*>(orow + d) = t;
    }
}

// ---------------------------------------------------------------------------
extern "C" void kernel_launch(void* const* d_in, const int* in_sizes, int n_in,
                              void* d_out, int out_size, void* d_ws, size_t ws_size,
                              hipStream_t stream)
{
    const float* x  = (const float*)d_in[0];
    const float* wq = (const float*)d_in[1];
    const float* bq = (const float*)d_in[2];
    const float* wk = (const float*)d_in[3];
    const float* bk = (const float*)d_in[4];
    const float* wv = (const float*)d_in[5];
    const float* bv = (const float*)d_in[6];
    const float* wo = (const float*)d_in[7];
    const float* bo = (const float*)d_in[8];
    float* out = (float*)d_out;

    float* ws = (float*)d_ws;
    const size_t per = (size_t)M_ROWS * EMB;   // 13,436,928 elems

    // fp32 activation buffers
    float* qb = ws;
    float* kb = ws + per;
    float* vb = ws + 2 * per;
    float* ab = ws + 3 * per;

    // xb (bf16 input) overlaps ab's slot: dead before attention writes ab
    unsigned short* xb = (unsigned short*)(ws + 3 * per);

    // transposed bf16 weights after the fp32 region
    const size_t WSZ = (size_t)EMB * EMB;      // 1,327,104 elems
    unsigned short* wt   = (unsigned short*)(ws + 4 * per);
    unsigned short* wtq  = wt;
    unsigned short* wtk  = wt + WSZ;
    unsigned short* wtv  = wt + 2 * WSZ;
    unsigned short* wohi = wt + 3 * WSZ;
    unsigned short* wolo = wt + 4 * WSZ;

    // hi/lo split of attention output reuses qb's slot (dead after attention)
    unsigned short* abhi = (unsigned short*)ws;
    unsigned short* ablo = (unsigned short*)ws + per;

    const int n8 = (int)(per / 8);             // 1,679,616
    dim3 cvtg((n8 + 255) / 256);
    dim3 tg(36, 36);
    dim3 gg(92, 9);                            // ceil(11664/128) x 1152/128
    dim3 bb(256);

    // convert inputs
    cvt_bf16_kernel<<<cvtg, bb, 0, stream>>>(x, xb, n8);
    tcvt_kernel<false><<<tg, bb, 0, stream>>>(wq, wtq, nullptr);
    tcvt_kernel<false><<<tg, bb, 0, stream>>>(wk, wtk, nullptr);
    tcvt_kernel<false><<<tg, bb, 0, stream>>>(wv, wtv, nullptr);

    // QKV projections (plain bf16 MFMA)
    mfma_gemm_kernel<false><<<gg, bb, 0, stream>>>(xb, wtq, bq, qb);
    mfma_gemm_kernel<false><<<gg, bb, 0, stream>>>(xb, wtk, bk, kb);
    mfma_gemm_kernel<false><<<gg, bb, 0, stream>>>(xb, wtv, bv, vb);

    // attention (fp32, unchanged)
    dim3 ga(B_SZ * NH, (S_LEN + 255) / 256);
    attn_kernel<<<ga, bb, 0, stream>>>(qb, kb, vb, ab);

    // out-projection: hi/lo split, 3 accumulating passes
    cvt_split_kernel<<<cvtg, bb, 0, stream>>>(ab, abhi, ablo, n8);
    tcvt_kernel<true><<<tg, bb, 0, stream>>>(wo, wohi, wolo);
    mfma_gemm_kernel<false><<<gg, bb, 0, stream>>>(abhi, wohi, bo, out);
    mfma_gemm_kernel<true><<<gg, bb, 0, stream>>>(abhi, wolo, nullptr, out);
    mfma_gemm_kernel<true><<<gg, bb, 0, stream>>>(ablo, wohi, nullptr, out);
}

// Round 5
// 1397.218 us; speedup vs baseline: 2.3407x; 1.8723x over previous
//
#include <hip/hip_runtime.h>
#include <math.h>

// Problem constants
#define B_SZ 16
#define S_LEN 729
#define EMB 1152
#define NH 16
#define DH 72
#define SCALE 0.11785113019775792f  // 72^-0.5
#define M_ROWS (B_SZ * S_LEN)       // 11664
#define SPAD 768
#define DPAD 96
#define QT_PER 12                   // ceil(729/64) q-tiles and kv-tiles

typedef __bf16 bf16x8 __attribute__((ext_vector_type(8)));
typedef float  f32x4  __attribute__((ext_vector_type(4)));

__device__ __forceinline__ unsigned short f32_bf16(float f) {
    unsigned int u = __float_as_uint(f);
    u = (u + 0x7FFFu + ((u >> 16) & 1u)) >> 16;   // RNE
    return (unsigned short)u;
}
__device__ __forceinline__ float bf16_f32(unsigned short h) {
    return __uint_as_float(((unsigned int)h) << 16);
}

// ---------------------------------------------------------------------------
// fp32 -> bf16 convert (8 elems/thread)
// ---------------------------------------------------------------------------
__global__ __launch_bounds__(256) void cvt_bf16_kernel(
    const float* __restrict__ in, unsigned short* __restrict__ out, int n8)
{
    int i = blockIdx.x * 256 + threadIdx.x;
    if (i >= n8) return;
    const float4* p = reinterpret_cast<const float4*>(in) + 2 * (size_t)i;
    float4 a = p[0], b = p[1];
    uint4 o;
    o.x = (unsigned int)f32_bf16(a.x) | ((unsigned int)f32_bf16(a.y) << 16);
    o.y = (unsigned int)f32_bf16(a.z) | ((unsigned int)f32_bf16(a.w) << 16);
    o.z = (unsigned int)f32_bf16(b.x) | ((unsigned int)f32_bf16(b.y) << 16);
    o.w = (unsigned int)f32_bf16(b.z) | ((unsigned int)f32_bf16(b.w) << 16);
    reinterpret_cast<uint4*>(out)[i] = o;
}

// ---------------------------------------------------------------------------
// Transpose + convert: W fp32 [K][N] -> Wt bf16 [N][K] (+ optional lo split)
// ---------------------------------------------------------------------------
template<bool SPLIT>
__global__ __launch_bounds__(256) void tcvt_kernel(
    const float* __restrict__ W, unsigned short* __restrict__ Th,
    unsigned short* __restrict__ Tl)
{
    __shared__ float Ts[32][33];
    const int bk = blockIdx.x, bn = blockIdx.y;
    const int t = threadIdx.x;
    const int r  = t >> 3;
    const int c4 = (t & 7) * 4;
    float4 f = *reinterpret_cast<const float4*>(W + (size_t)(bk * 32 + r) * EMB + bn * 32 + c4);
    Ts[r][c4] = f.x; Ts[r][c4 + 1] = f.y; Ts[r][c4 + 2] = f.z; Ts[r][c4 + 3] = f.w;
    __syncthreads();
    float v[4];
#pragma unroll
    for (int i = 0; i < 4; ++i) v[i] = Ts[c4 + i][r];
    unsigned short h[4];
#pragma unroll
    for (int i = 0; i < 4; ++i) h[i] = f32_bf16(v[i]);
    uint2 oh;
    oh.x = h[0] | ((unsigned int)h[1] << 16);
    oh.y = h[2] | ((unsigned int)h[3] << 16);
    *reinterpret_cast<uint2*>(Th + (size_t)(bn * 32 + r) * EMB + bk * 32 + c4) = oh;
    if (SPLIT) {
        unsigned short l[4];
#pragma unroll
        for (int i = 0; i < 4; ++i) l[i] = f32_bf16(v[i] - bf16_f32(h[i]));
        uint2 ol;
        ol.x = l[0] | ((unsigned int)l[1] << 16);
        ol.y = l[2] | ((unsigned int)l[3] << 16);
        *reinterpret_cast<uint2*>(Tl + (size_t)(bn * 32 + r) * EMB + bk * 32 + c4) = ol;
    }
}

// ---------------------------------------------------------------------------
// bf16 MFMA GEMM (unchanged, verified round 3)
// ---------------------------------------------------------------------------
template<bool ACCUM>
__global__ __launch_bounds__(256) void mfma_gemm_kernel(
    const unsigned short* __restrict__ A,
    const unsigned short* __restrict__ Wt,
    const float* __restrict__ bias,
    float* __restrict__ C)
{
    __shared__ __align__(16) unsigned short As[2][128 * 32];
    __shared__ __align__(16) unsigned short Ws[2][128 * 32];

    const int tid  = threadIdx.x;
    const int lane = tid & 63;
    const int wid  = tid >> 6;
    const int wr   = wid >> 1;
    const int wc   = wid & 1;
    const int row0 = blockIdx.x * 128;
    const int col0 = blockIdx.y * 128;

    const int srow = tid >> 2;
    const int sch  = tid & 3;

    f32x4 acc[4][4];
#pragma unroll
    for (int i = 0; i < 4; ++i)
#pragma unroll
        for (int j = 0; j < 4; ++j) acc[i][j] = (f32x4){0.f, 0.f, 0.f, 0.f};

    uint4 avr[2], wvr[2];

    auto loadAW = [&](int k0) {
#pragma unroll
        for (int s = 0; s < 2; ++s) {
            int ra = row0 + s * 64 + srow;
            if (ra > M_ROWS - 1) ra = M_ROWS - 1;
            avr[s] = *reinterpret_cast<const uint4*>(A + (size_t)ra * EMB + k0 + sch * 8);
            const int rw = col0 + s * 64 + srow;
            wvr[s] = *reinterpret_cast<const uint4*>(Wt + (size_t)rw * EMB + k0 + sch * 8);
        }
    };
    auto storeLDS = [&](int b) {
#pragma unroll
        for (int s = 0; s < 2; ++s) {
            *reinterpret_cast<uint4*>(&As[b][(s * 64 + srow) * 32 + sch * 8]) = avr[s];
            *reinterpret_cast<uint4*>(&Ws[b][(s * 64 + srow) * 32 + sch * 8]) = wvr[s];
        }
    };

    loadAW(0);
    storeLDS(0);
    __syncthreads();

    const int NK = EMB / 32;
    for (int t = 0; t < NK; ++t) {
        if (t + 1 < NK) loadAW((t + 1) * 32);
        const int b = t & 1;
        bf16x8 af[4], bfr[4];
#pragma unroll
        for (int i = 0; i < 4; ++i)
            af[i] = *reinterpret_cast<const bf16x8*>(
                &As[b][(wr * 64 + i * 16 + (lane & 15)) * 32 + (lane >> 4) * 8]);
#pragma unroll
        for (int j = 0; j < 4; ++j)
            bfr[j] = *reinterpret_cast<const bf16x8*>(
                &Ws[b][(wc * 64 + j * 16 + (lane & 15)) * 32 + (lane >> 4) * 8]);
#pragma unroll
        for (int i = 0; i < 4; ++i)
#pragma unroll
            for (int j = 0; j < 4; ++j)
                acc[i][j] = __builtin_amdgcn_mfma_f32_16x16x32_bf16(af[i], bfr[j], acc[i][j], 0, 0, 0);
        if (t + 1 < NK) storeLDS(b ^ 1);
        __syncthreads();
    }

    const int crow = (lane >> 4) * 4;
    const int ccol = lane & 15;
#pragma unroll
    for (int j = 0; j < 4; ++j) {
        const int cg = col0 + wc * 64 + j * 16 + ccol;
        float bj = 0.f;
        if (!ACCUM) bj = bias[cg];
#pragma unroll
        for (int i = 0; i < 4; ++i) {
            const int rbase = row0 + wr * 64 + i * 16 + crow;
#pragma unroll
            for (int r = 0; r < 4; ++r) {
                const int rg = rbase + r;
                if (rg < M_ROWS) {
                    const size_t idx = (size_t)rg * EMB + cg;
                    if (ACCUM) C[idx] += acc[i][j][r];
                    else       C[idx]  = acc[i][j][r] + bj;
                }
            }
        }
    }
}

// ---------------------------------------------------------------------------
// Repack fp32 [B,S,EMB] head-layout -> bf16 [bh][SPAD][DPAD] with TOTAL
// zero-fill coverage (s >= 729 rows and dh chunks 9..11 are written to 0).
// NaN fix: staged K/Q tiles must never contain stale overlay bytes.
// ---------------------------------------------------------------------------
__global__ __launch_bounds__(256) void repack_qk_kernel(
    const float* __restrict__ src, unsigned short* __restrict__ dst, float scale)
{
    int gid = blockIdx.x * 256 + threadIdx.x;   // total = 256 * SPAD * 12
    int c  = gid % 12;
    int t  = gid / 12;
    int s  = t % SPAD;
    int bh = t / SPAD;
    int b = bh >> 4, h = bh & 15;
    uint4 o = make_uint4(0u, 0u, 0u, 0u);
    if (s < S_LEN && c < 9) {
        const float* p = src + (size_t)(b * S_LEN + s) * EMB + h * DH + c * 8;
        float4 a = *reinterpret_cast<const float4*>(p);
        float4 v = *reinterpret_cast<const float4*>(p + 4);
        unsigned short hh[8];
        hh[0] = f32_bf16(a.x * scale); hh[1] = f32_bf16(a.y * scale);
        hh[2] = f32_bf16(a.z * scale); hh[3] = f32_bf16(a.w * scale);
        hh[4] = f32_bf16(v.x * scale); hh[5] = f32_bf16(v.y * scale);
        hh[6] = f32_bf16(v.z * scale); hh[7] = f32_bf16(v.w * scale);
        o.x = hh[0] | ((unsigned int)hh[1] << 16);
        o.y = hh[2] | ((unsigned int)hh[3] << 16);
        o.z = hh[4] | ((unsigned int)hh[5] << 16);
        o.w = hh[6] | ((unsigned int)hh[7] << 16);
    }
    *reinterpret_cast<uint4*>(dst + ((size_t)bh * SPAD + s) * DPAD + c * 8) = o;
}

// ---------------------------------------------------------------------------
// Repack V fp32 [B,S,EMB] -> Vt bf16 [bh][DPAD][SPAD] (transpose per head).
// d rows 72..95 and s >= 729 zero-filled (total coverage).
// ---------------------------------------------------------------------------
__global__ __launch_bounds__(256) void repack_vt_kernel(
    const float* __restrict__ src, unsigned short* __restrict__ dst)
{
    __shared__ float Vs[64][76];
    const int bh = blockIdx.x, st0 = blockIdx.y * 64;
    const int b = bh >> 4, h = bh & 15;
    const int tid = threadIdx.x;
    for (int i = tid; i < 64 * 18; i += 256) {
        int r = i / 18, c = i % 18;
        int s = st0 + r;
        float4 v = make_float4(0.f, 0.f, 0.f, 0.f);
        if (s < S_LEN)
            v = *reinterpret_cast<const float4*>(src + (size_t)(b * S_LEN + s) * EMB + h * DH + c * 4);
        Vs[r][c * 4 + 0] = v.x; Vs[r][c * 4 + 1] = v.y;
        Vs[r][c * 4 + 2] = v.z; Vs[r][c * 4 + 3] = v.w;
    }
    __syncthreads();
    for (int i = tid; i < DPAD * 8; i += 256) {   // full 96 rows
        int d = i / 8, sc = i % 8;
        unsigned short hh[8];
#pragma unroll
        for (int t = 0; t < 8; ++t) hh[t] = (d < DH) ? f32_bf16(Vs[sc * 8 + t][d]) : 0;
        uint4 o;
        o.x = hh[0] | ((unsigned int)hh[1] << 16);
        o.y = hh[2] | ((unsigned int)hh[3] << 16);
        o.z = hh[4] | ((unsigned int)hh[5] << 16);
        o.w = hh[6] | ((unsigned int)hh[7] << 16);
        *reinterpret_cast<uint4*>(dst + ((size_t)bh * DPAD + d) * SPAD + st0 + sc * 8) = o;
    }
}

// ---------------------------------------------------------------------------
// MFMA flash attention. Block = (bh, q-tile of 64), 4 waves x 16 q-rows.
// Swapped QK^T (S^T = K·Q^T) -> lane owns q = lane&15; online softmax lane-
// local. PV as out^T = Vt·P^T. Writes hi/lo bf16 split of output directly.
// ---------------------------------------------------------------------------
__global__ __launch_bounds__(256) void mfma_attn_kernel(
    const unsigned short* __restrict__ Qg, const unsigned short* __restrict__ Kg,
    const unsigned short* __restrict__ Vtg,
    unsigned short* __restrict__ outHi, unsigned short* __restrict__ outLo)
{
    // XCD-aware bijective swizzle: 3072 blocks = 8 * 384
    const int id  = blockIdx.x;
    const int nid = (id & 7) * 384 + (id >> 3);
    const int bh  = nid / QT_PER, qt = nid % QT_PER;
    const int b   = bh >> 4, h = bh & 15;

    const int tid = threadIdx.x, lane = tid & 63, w = tid >> 6;
    const int g = lane >> 4, q16 = lane & 15;

    __shared__ __align__(16) unsigned short Ks[64][104];    // K-tile, pad 104 (2-way only)
    __shared__ __align__(16) unsigned short Vts[96][64];    // Vt-tile, XOR-swizzled chunks
    __shared__ __align__(16) unsigned short Ps[4][16][64];  // per-wave P^T, XOR-swizzled

    // Q fragments (reused across all KV tiles): B-frag of Q^T
    const int qrow = qt * 64 + w * 16 + q16;                // < SPAD
    const unsigned short* qptr = Qg + ((size_t)bh * SPAD + qrow) * DPAD;
    bf16x8 qf[3];
#pragma unroll
    for (int c = 0; c < 3; ++c)
        qf[c] = *reinterpret_cast<const bf16x8*>(qptr + c * 32 + g * 8);

    f32x4 oacc[5];
#pragma unroll
    for (int dt = 0; dt < 5; ++dt) oacc[dt] = (f32x4){0.f, 0.f, 0.f, 0.f};
    float m_run = -INFINITY, l_run = 0.f;

    for (int j = 0; j < 12; ++j) {
        const int kbase = j * 64;
        // stage K tile: 64 rows x 96 = 768 uint4
        for (int i = tid; i < 768; i += 256) {
            int r = i / 12, c = i % 12;
            uint4 v = *reinterpret_cast<const uint4*>(
                Kg + ((size_t)bh * SPAD + kbase + r) * DPAD + c * 8);
            *reinterpret_cast<uint4*>(&Ks[r][c * 8]) = v;
        }
        // stage Vt tile: 96 rows x 64 = 768 uint4, swizzled
        for (int i = tid; i < 768; i += 256) {
            int d = i >> 3, c = i & 7;
            uint4 v = *reinterpret_cast<const uint4*>(
                Vtg + ((size_t)bh * DPAD + d) * SPAD + kbase + c * 8);
            *reinterpret_cast<uint4*>(&Vts[d][(c ^ (d & 7)) * 8]) = v;
        }
        __syncthreads();

        // QK^T: S^T[k][q], k-tiles t=0..3
        f32x4 st[4];
#pragma unroll
        for (int t = 0; t < 4; ++t) {
            st[t] = (f32x4){0.f, 0.f, 0.f, 0.f};
#pragma unroll
            for (int c = 0; c < 3; ++c) {
                bf16x8 kf = *reinterpret_cast<const bf16x8*>(
                    &Ks[t * 16 + q16][c * 32 + g * 8]);
                st[t] = __builtin_amdgcn_mfma_f32_16x16x32_bf16(kf, qf[c], st[t], 0, 0, 0);
            }
        }
        // mask invalid keys (last tile only)
        if (j == 11) {
#pragma unroll
            for (int t = 0; t < 4; ++t)
#pragma unroll
                for (int r = 0; r < 4; ++r)
                    if (kbase + t * 16 + g * 4 + r >= S_LEN) st[t][r] = -1e30f;
        }

        // online softmax (scores pre-scaled via Q repack)
        float pm = -INFINITY;
#pragma unroll
        for (int t = 0; t < 4; ++t)
#pragma unroll
            for (int r = 0; r < 4; ++r) pm = fmaxf(pm, st[t][r]);
        pm = fmaxf(pm, __shfl_xor(pm, 16));
        pm = fmaxf(pm, __shfl_xor(pm, 32));
        const float mnew = fmaxf(m_run, pm);
        const float corr = __expf(m_run - mnew);
        float p[4][4];
        float ls = 0.f;
#pragma unroll
        for (int t = 0; t < 4; ++t)
#pragma unroll
            for (int r = 0; r < 4; ++r) {
                p[t][r] = __expf(st[t][r] - mnew);
                ls += p[t][r];
            }
        ls += __shfl_xor(ls, 16);
        ls += __shfl_xor(ls, 32);
        l_run = l_run * corr + ls;
        m_run = mnew;
#pragma unroll
        for (int dt = 0; dt < 5; ++dt) oacc[dt] *= corr;

        // write P^T (bf16) to per-wave LDS: row q16, k = t*16+g*4+r, swizzled chunks
#pragma unroll
        for (int t = 0; t < 4; ++t) {
            uint2 up;
            up.x = f32_bf16(p[t][0]) | ((unsigned int)f32_bf16(p[t][1]) << 16);
            up.y = f32_bf16(p[t][2]) | ((unsigned int)f32_bf16(p[t][3]) << 16);
            int ch = (2 * t + (g >> 1)) ^ (q16 & 7);
            *reinterpret_cast<uint2*>(
                reinterpret_cast<char*>(&Ps[w][q16][0]) + ch * 16 + (g & 1) * 8) = up;
        }

        // PV: out^T[d][q] += Vt · P^T   (wave-private Ps, no barrier needed)
#pragma unroll
        for (int kc = 0; kc < 2; ++kc) {
            const int k0 = kc * 32;
            int pch = ((k0 >> 3) + g) ^ (q16 & 7);
            bf16x8 pf = *reinterpret_cast<const bf16x8*>(
                reinterpret_cast<char*>(&Ps[w][q16][0]) + pch * 16);
#pragma unroll
            for (int dt = 0; dt < 5; ++dt) {
                const int drow = dt * 16 + q16;
                int vch = ((k0 >> 3) + g) ^ (drow & 7);
                bf16x8 vf = *reinterpret_cast<const bf16x8*>(&Vts[drow][vch * 8]);
                oacc[dt] = __builtin_amdgcn_mfma_f32_16x16x32_bf16(vf, pf, oacc[dt], 0, 0, 0);
            }
        }
        __syncthreads();   // before next tile's staging overwrites Ks/Vts
    }

    // epilogue: lane holds out^T[d = dt*16+g*4+r][q=q16]; write hi/lo split
    const int q_local = qt * 64 + w * 16 + q16;
    if (q_local < S_LEN) {
        const float inv = 1.f / l_run;
        const size_t mrow = (size_t)b * S_LEN + q_local;
#pragma unroll
        for (int dt = 0; dt < 5; ++dt) {
            const int d0 = dt * 16 + g * 4;
            if (d0 < DH) {
                unsigned short hh[4], ll[4];
#pragma unroll
                for (int r = 0; r < 4; ++r) {
                    float o = oacc[dt][r] * inv;
                    hh[r] = f32_bf16(o);
                    ll[r] = f32_bf16(o - bf16_f32(hh[r]));
                }
                uint2 oh, ol;
                oh.x = hh[0] | ((unsigned int)hh[1] << 16);
                oh.y = hh[2] | ((unsigned int)hh[3] << 16);
                ol.x = ll[0] | ((unsigned int)ll[1] << 16);
                ol.y = ll[2] | ((unsigned int)ll[3] << 16);
                const size_t off = mrow * EMB + h * DH + d0;
                *reinterpret_cast<uint2*>(outHi + off) = oh;
                *reinterpret_cast<uint2*>(outLo + off) = ol;
            }
        }
    }
}

// ---------------------------------------------------------------------------
extern "C" void kernel_launch(void* const* d_in, const int* in_sizes, int n_in,
                              void* d_out, int out_size, void* d_ws, size_t ws_size,
                              hipStream_t stream)
{
    const float* x  = (const float*)d_in[0];
    const float* wq = (const float*)d_in[1];
    const float* bq = (const float*)d_in[2];
    const float* wk = (const float*)d_in[3];
    const float* bk = (const float*)d_in[4];
    const float* wv = (const float*)d_in[5];
    const float* bv = (const float*)d_in[6];
    const float* wo = (const float*)d_in[7];
    const float* bo = (const float*)d_in[8];
    float* out = (float*)d_out;

    float* ws = (float*)d_ws;
    const size_t per = (size_t)M_ROWS * EMB;        // 13,436,928 elems

    // fp32 staging regions (time-shared):
    float* qb = ws;                                  // R0, later hosts Kg
    float* kb = ws + per;                            // R1, later hosts Vtg
    float* vb = ws + 2 * per;                        // R2, later hosts outHi/outLo

    const size_t QG_F32 = ((size_t)256 * SPAD * DPAD * 2 + 3) / 4;   // bf16 bytes -> f32 units
    unsigned short* Qg   = (unsigned short*)(ws + 3 * per);          // R3
    unsigned short* xb   = (unsigned short*)(ws + 3 * per + QG_F32); // R4
    unsigned short* wt   = (unsigned short*)((float*)xb + per / 2);  // R5
    unsigned short* Kg   = (unsigned short*)qb;                      // overlays R0 (after repackQ)
    unsigned short* Vtg  = (unsigned short*)kb;                      // overlays R1 (after repackK)
    unsigned short* outHi = (unsigned short*)vb;                     // overlays R2 (after repackV)
    unsigned short* outLo = outHi + per;

    const size_t WSZ = (size_t)EMB * EMB;
    unsigned short* wtq  = wt;
    unsigned short* wtk  = wt + WSZ;
    unsigned short* wtv  = wt + 2 * WSZ;
    unsigned short* wohi = wt + 3 * WSZ;
    unsigned short* wolo = wt + 4 * WSZ;

    const int n8 = (int)(per / 8);
    dim3 cvtg((n8 + 255) / 256);       // 6561
    dim3 tg(36, 36);
    dim3 gg(92, 9);
    dim3 bb(256);

    // input conversions
    cvt_bf16_kernel<<<cvtg, bb, 0, stream>>>(x, xb, n8);
    tcvt_kernel<false><<<tg, bb, 0, stream>>>(wq, wtq, nullptr);
    tcvt_kernel<false><<<tg, bb, 0, stream>>>(wk, wtk, nullptr);
    tcvt_kernel<false><<<tg, bb, 0, stream>>>(wv, wtv, nullptr);
    tcvt_kernel<true><<<tg, bb, 0, stream>>>(wo, wohi, wolo);

    // QKV projections + repacks (ordering honors region overlays)
    const int rq_blocks = (256 * SPAD * 12) / 256;   // 9216
    mfma_gemm_kernel<false><<<gg, bb, 0, stream>>>(xb, wtq, bq, qb);
    repack_qk_kernel<<<dim3(rq_blocks), bb, 0, stream>>>(qb, Qg, SCALE);  // qb -> R3
    mfma_gemm_kernel<false><<<gg, bb, 0, stream>>>(xb, wtk, bk, kb);
    repack_qk_kernel<<<dim3(rq_blocks), bb, 0, stream>>>(kb, Kg, 1.0f);   // kb -> R0
    mfma_gemm_kernel<false><<<gg, bb, 0, stream>>>(xb, wtv, bv, vb);
    dim3 vg(256, 12);
    repack_vt_kernel<<<vg, bb, 0, stream>>>(vb, Vtg);                     // vb -> R1

    // flash attention (writes hi/lo split into R2)
    mfma_attn_kernel<<<dim3(256 * QT_PER), bb, 0, stream>>>(Qg, Kg, Vtg, outHi, outLo);

    // out-projection: hi/lo 3-pass accumulate
    mfma_gemm_kernel<false><<<gg, bb, 0, stream>>>(outHi, wohi, bo, out);
    mfma_gemm_kernel<true><<<gg, bb, 0, stream>>>(outHi, wolo, nullptr, out);
    mfma_gemm_kernel<true><<<gg, bb, 0, stream>>>(outLo, wohi, nullptr, out);
}

// Round 6
// 694.708 us; speedup vs baseline: 4.7077x; 2.0112x over previous
//
#include <hip/hip_runtime.h>
#include <math.h>

// Problem constants
#define B_SZ 16
#define S_LEN 729
#define EMB 1152
#define NH 16
#define DH 72
#define SCALE 0.11785113019775792f  // 72^-0.5
#define M_ROWS (B_SZ * S_LEN)       // 11664
#define M_PAD  (92 * 128)           // 11776 (grid-x * 128)
#define SPAD 768
#define DPAD 96
#define QT_PER 12

typedef __bf16 bf16x8 __attribute__((ext_vector_type(8)));
typedef float  f32x4  __attribute__((ext_vector_type(4)));

// async global->LDS, 16B per lane. LDS dest must be base + lane*16 (m104).
#define GLD16(g, l) __builtin_amdgcn_global_load_lds( \
    (const __attribute__((address_space(1))) unsigned int*)(const void*)(g), \
    (__attribute__((address_space(3))) unsigned int*)(void*)(l), 16, 0, 0)

__device__ __forceinline__ unsigned short f32_bf16(float f) {
    unsigned int u = __float_as_uint(f);
    u = (u + 0x7FFFu + ((u >> 16) & 1u)) >> 16;   // RNE
    return (unsigned short)u;
}
__device__ __forceinline__ float bf16_f32(unsigned short h) {
    return __uint_as_float(((unsigned int)h) << 16);
}

// ---------------------------------------------------------------------------
// fp32 -> bf16 convert with zero-fill past n8_valid (padded activation rows)
// ---------------------------------------------------------------------------
__global__ __launch_bounds__(256) void cvt_bf16_pad_kernel(
    const float* __restrict__ in, unsigned short* __restrict__ out,
    int n8_valid, int n8_total)
{
    int i = blockIdx.x * 256 + threadIdx.x;
    if (i >= n8_total) return;
    uint4 o = make_uint4(0u, 0u, 0u, 0u);
    if (i < n8_valid) {
        const float4* p = reinterpret_cast<const float4*>(in) + 2 * (size_t)i;
        float4 a = p[0], b = p[1];
        o.x = (unsigned int)f32_bf16(a.x) | ((unsigned int)f32_bf16(a.y) << 16);
        o.y = (unsigned int)f32_bf16(a.z) | ((unsigned int)f32_bf16(a.w) << 16);
        o.z = (unsigned int)f32_bf16(b.x) | ((unsigned int)f32_bf16(b.y) << 16);
        o.w = (unsigned int)f32_bf16(b.z) | ((unsigned int)f32_bf16(b.w) << 16);
    }
    reinterpret_cast<uint4*>(out)[i] = o;
}

// ---------------------------------------------------------------------------
// Transpose + convert: W fp32 [K][N] -> Wt bf16 [N][K] (+ optional lo split)
// ---------------------------------------------------------------------------
template<bool SPLIT>
__global__ __launch_bounds__(256) void tcvt_kernel(
    const float* __restrict__ W, unsigned short* __restrict__ Th,
    unsigned short* __restrict__ Tl)
{
    __shared__ float Ts[32][33];
    const int bk = blockIdx.x, bn = blockIdx.y;
    const int t = threadIdx.x;
    const int r  = t >> 3;
    const int c4 = (t & 7) * 4;
    float4 f = *reinterpret_cast<const float4*>(W + (size_t)(bk * 32 + r) * EMB + bn * 32 + c4);
    Ts[r][c4] = f.x; Ts[r][c4 + 1] = f.y; Ts[r][c4 + 2] = f.z; Ts[r][c4 + 3] = f.w;
    __syncthreads();
    float v[4];
#pragma unroll
    for (int i = 0; i < 4; ++i) v[i] = Ts[c4 + i][r];
    unsigned short h[4];
#pragma unroll
    for (int i = 0; i < 4; ++i) h[i] = f32_bf16(v[i]);
    uint2 oh;
    oh.x = h[0] | ((unsigned int)h[1] << 16);
    oh.y = h[2] | ((unsigned int)h[3] << 16);
    *reinterpret_cast<uint2*>(Th + (size_t)(bn * 32 + r) * EMB + bk * 32 + c4) = oh;
    if (SPLIT) {
        unsigned short l[4];
#pragma unroll
        for (int i = 0; i < 4; ++i) l[i] = f32_bf16(v[i] - bf16_f32(h[i]));
        uint2 ol;
        ol.x = l[0] | ((unsigned int)l[1] << 16);
        ol.y = l[2] | ((unsigned int)l[3] << 16);
        *reinterpret_cast<uint2*>(Tl + (size_t)(bn * 32 + r) * EMB + bk * 32 + c4) = ol;
    }
}

// ---------------------------------------------------------------------------
// m97-structure bf16 MFMA GEMM: C[M][1152] = A[M_PAD][1152] @ Wt[1152][1152]^T
// + bias. global_load_lds(16B) staging, double-buffered linear LDS [128][32].
// 128x128 tile, BK=32, 4 waves (2x2), 4x4 x 16x16x32 MFMA per wave.
// ---------------------------------------------------------------------------
__global__ __launch_bounds__(256) void mfma_gemm_kernel(
    const unsigned short* __restrict__ A,
    const unsigned short* __restrict__ Wt,
    const float* __restrict__ bias,
    float* __restrict__ C)
{
    __shared__ __align__(16) unsigned short As[2][128 * 32];
    __shared__ __align__(16) unsigned short Ws[2][128 * 32];

    const int tid  = threadIdx.x;
    const int lane = tid & 63;
    const int wid  = tid >> 6;
    const int wr   = wid >> 1;
    const int wc   = wid & 1;
    const int row0 = blockIdx.x * 128;
    const int col0 = blockIdx.y * 128;

    f32x4 acc[4][4];
#pragma unroll
    for (int i = 0; i < 4; ++i)
#pragma unroll
        for (int j = 0; j < 4; ++j) acc[i][j] = (f32x4){0.f, 0.f, 0.f, 0.f};

    // stage: 128 rows x 64B = 512 x 16B chunks per tile; 2 rounds of 256 lanes.
    // idx = r2*256 + tid -> row = idx>>2, ch = idx&3; LDS off = idx*16B (= base+lane*16)
    auto stage = [&](int buf, int k0) {
#pragma unroll
        for (int r2 = 0; r2 < 2; ++r2) {
            const int idx = r2 * 256 + tid;
            const int row = idx >> 2, ch = idx & 3;
            GLD16(A  + (size_t)(row0 + row) * EMB + k0 + ch * 8, &As[buf][idx * 8]);
            GLD16(Wt + (size_t)(col0 + row) * EMB + k0 + ch * 8, &Ws[buf][idx * 8]);
        }
    };

    stage(0, 0);
    __syncthreads();   // drains vmcnt(0): buf0 ready

    const int NK = EMB / 32;   // 36
    int buf = 0;
    for (int t = 0; t < NK; ++t) {
        if (t + 1 < NK) stage(buf ^ 1, (t + 1) * 32);
        bf16x8 af[4], bfr[4];
#pragma unroll
        for (int i = 0; i < 4; ++i)
            af[i] = *reinterpret_cast<const bf16x8*>(
                &As[buf][(wr * 64 + i * 16 + (lane & 15)) * 32 + (lane >> 4) * 8]);
#pragma unroll
        for (int j = 0; j < 4; ++j)
            bfr[j] = *reinterpret_cast<const bf16x8*>(
                &Ws[buf][(wc * 64 + j * 16 + (lane & 15)) * 32 + (lane >> 4) * 8]);
#pragma unroll
        for (int i = 0; i < 4; ++i)
#pragma unroll
            for (int j = 0; j < 4; ++j)
                acc[i][j] = __builtin_amdgcn_mfma_f32_16x16x32_bf16(af[i], bfr[j], acc[i][j], 0, 0, 0);
        __syncthreads();   // drains vmcnt(0) -> next buf ready; protects buf reuse
        buf ^= 1;
    }

    const int crow = (lane >> 4) * 4;
    const int ccol = lane & 15;
#pragma unroll
    for (int j = 0; j < 4; ++j) {
        const int cg = col0 + wc * 64 + j * 16 + ccol;
        const float bj = bias[cg];
#pragma unroll
        for (int i = 0; i < 4; ++i) {
            const int rbase = row0 + wr * 64 + i * 16 + crow;
#pragma unroll
            for (int r = 0; r < 4; ++r) {
                const int rg = rbase + r;
                if (rg < M_ROWS) C[(size_t)rg * EMB + cg] = acc[i][j][r] + bj;
            }
        }
    }
}

// ---------------------------------------------------------------------------
// Fused 3-term out-projection: C = Ah*Wh + Ah*Wl + Al*Wh + bias.
// Same structure; 4 staged tiles (64KB LDS dbuf), 48 MFMA per K-step.
// ---------------------------------------------------------------------------
__global__ __launch_bounds__(256) void mfma_gemm3_kernel(
    const unsigned short* __restrict__ Ah, const unsigned short* __restrict__ Al,
    const unsigned short* __restrict__ Wh, const unsigned short* __restrict__ Wl,
    const float* __restrict__ bias, float* __restrict__ C)
{
    __shared__ __align__(16) unsigned short Ahs[2][128 * 32];
    __shared__ __align__(16) unsigned short Als[2][128 * 32];
    __shared__ __align__(16) unsigned short Whs[2][128 * 32];
    __shared__ __align__(16) unsigned short Wls[2][128 * 32];

    const int tid  = threadIdx.x;
    const int lane = tid & 63;
    const int wid  = tid >> 6;
    const int wr   = wid >> 1;
    const int wc   = wid & 1;
    const int row0 = blockIdx.x * 128;
    const int col0 = blockIdx.y * 128;

    f32x4 acc[4][4];
#pragma unroll
    for (int i = 0; i < 4; ++i)
#pragma unroll
        for (int j = 0; j < 4; ++j) acc[i][j] = (f32x4){0.f, 0.f, 0.f, 0.f};

    auto stage = [&](int buf, int k0) {
#pragma unroll
        for (int r2 = 0; r2 < 2; ++r2) {
            const int idx = r2 * 256 + tid;
            const int row = idx >> 2, ch = idx & 3;
            const size_t aoff = (size_t)(row0 + row) * EMB + k0 + ch * 8;
            const size_t woff = (size_t)(col0 + row) * EMB + k0 + ch * 8;
            GLD16(Ah + aoff, &Ahs[buf][idx * 8]);
            GLD16(Al + aoff, &Als[buf][idx * 8]);
            GLD16(Wh + woff, &Whs[buf][idx * 8]);
            GLD16(Wl + woff, &Wls[buf][idx * 8]);
        }
    };

    stage(0, 0);
    __syncthreads();

    const int NK = EMB / 32;
    int buf = 0;
    for (int t = 0; t < NK; ++t) {
        if (t + 1 < NK) stage(buf ^ 1, (t + 1) * 32);
        bf16x8 ah[4], al[4];
#pragma unroll
        for (int i = 0; i < 4; ++i) {
            const int off = (wr * 64 + i * 16 + (lane & 15)) * 32 + (lane >> 4) * 8;
            ah[i] = *reinterpret_cast<const bf16x8*>(&Ahs[buf][off]);
            al[i] = *reinterpret_cast<const bf16x8*>(&Als[buf][off]);
        }
#pragma unroll
        for (int j = 0; j < 4; ++j) {
            const int off = (wc * 64 + j * 16 + (lane & 15)) * 32 + (lane >> 4) * 8;
            bf16x8 wh = *reinterpret_cast<const bf16x8*>(&Whs[buf][off]);
            bf16x8 wl = *reinterpret_cast<const bf16x8*>(&Wls[buf][off]);
#pragma unroll
            for (int i = 0; i < 4; ++i) {
                acc[i][j] = __builtin_amdgcn_mfma_f32_16x16x32_bf16(ah[i], wh, acc[i][j], 0, 0, 0);
                acc[i][j] = __builtin_amdgcn_mfma_f32_16x16x32_bf16(ah[i], wl, acc[i][j], 0, 0, 0);
                acc[i][j] = __builtin_amdgcn_mfma_f32_16x16x32_bf16(al[i], wh, acc[i][j], 0, 0, 0);
            }
        }
        __syncthreads();
        buf ^= 1;
    }

    const int crow = (lane >> 4) * 4;
    const int ccol = lane & 15;
#pragma unroll
    for (int j = 0; j < 4; ++j) {
        const int cg = col0 + wc * 64 + j * 16 + ccol;
        const float bj = bias[cg];
#pragma unroll
        for (int i = 0; i < 4; ++i) {
            const int rbase = row0 + wr * 64 + i * 16 + crow;
#pragma unroll
            for (int r = 0; r < 4; ++r) {
                const int rg = rbase + r;
                if (rg < M_ROWS) C[(size_t)rg * EMB + cg] = acc[i][j][r] + bj;
            }
        }
    }
}

// ---------------------------------------------------------------------------
// Repack fp32 [B,S,EMB] head-layout -> bf16 [bh][SPAD][DPAD], total coverage
// (s >= 729 and dh chunks 9..11 zero-filled).
// ---------------------------------------------------------------------------
__global__ __launch_bounds__(256) void repack_qk_kernel(
    const float* __restrict__ src, unsigned short* __restrict__ dst, float scale)
{
    int gid = blockIdx.x * 256 + threadIdx.x;   // total = 256 * SPAD * 12
    int c  = gid % 12;
    int t  = gid / 12;
    int s  = t % SPAD;
    int bh = t / SPAD;
    int b = bh >> 4, h = bh & 15;
    uint4 o = make_uint4(0u, 0u, 0u, 0u);
    if (s < S_LEN && c < 9) {
        const float* p = src + (size_t)(b * S_LEN + s) * EMB + h * DH + c * 8;
        float4 a = *reinterpret_cast<const float4*>(p);
        float4 v = *reinterpret_cast<const float4*>(p + 4);
        unsigned short hh[8];
        hh[0] = f32_bf16(a.x * scale); hh[1] = f32_bf16(a.y * scale);
        hh[2] = f32_bf16(a.z * scale); hh[3] = f32_bf16(a.w * scale);
        hh[4] = f32_bf16(v.x * scale); hh[5] = f32_bf16(v.y * scale);
        hh[6] = f32_bf16(v.z * scale); hh[7] = f32_bf16(v.w * scale);
        o.x = hh[0] | ((unsigned int)hh[1] << 16);
        o.y = hh[2] | ((unsigned int)hh[3] << 16);
        o.z = hh[4] | ((unsigned int)hh[5] << 16);
        o.w = hh[6] | ((unsigned int)hh[7] << 16);
    }
    *reinterpret_cast<uint4*>(dst + ((size_t)bh * SPAD + s) * DPAD + c * 8) = o;
}

// ---------------------------------------------------------------------------
// Repack V fp32 [B,S,EMB] -> Vt bf16 [bh][DPAD][SPAD], total coverage.
// ---------------------------------------------------------------------------
__global__ __launch_bounds__(256) void repack_vt_kernel(
    const float* __restrict__ src, unsigned short* __restrict__ dst)
{
    __shared__ float Vs[64][76];
    const int bh = blockIdx.x, st0 = blockIdx.y * 64;
    const int b = bh >> 4, h = bh & 15;
    const int tid = threadIdx.x;
    for (int i = tid; i < 64 * 18; i += 256) {
        int r = i / 18, c = i % 18;
        int s = st0 + r;
        float4 v = make_float4(0.f, 0.f, 0.f, 0.f);
        if (s < S_LEN)
            v = *reinterpret_cast<const float4*>(src + (size_t)(b * S_LEN + s) * EMB + h * DH + c * 4);
        Vs[r][c * 4 + 0] = v.x; Vs[r][c * 4 + 1] = v.y;
        Vs[r][c * 4 + 2] = v.z; Vs[r][c * 4 + 3] = v.w;
    }
    __syncthreads();
    for (int i = tid; i < DPAD * 8; i += 256) {
        int d = i / 8, sc = i % 8;
        unsigned short hh[8];
#pragma unroll
        for (int t = 0; t < 8; ++t) hh[t] = (d < DH) ? f32_bf16(Vs[sc * 8 + t][d]) : 0;
        uint4 o;
        o.x = hh[0] | ((unsigned int)hh[1] << 16);
        o.y = hh[2] | ((unsigned int)hh[3] << 16);
        o.z = hh[4] | ((unsigned int)hh[5] << 16);
        o.w = hh[6] | ((unsigned int)hh[7] << 16);
        *reinterpret_cast<uint4*>(dst + ((size_t)bh * DPAD + d) * SPAD + st0 + sc * 8) = o;
    }
}

// ---------------------------------------------------------------------------
// MFMA flash attention (unchanged, verified round 5).
// ---------------------------------------------------------------------------
__global__ __launch_bounds__(256) void mfma_attn_kernel(
    const unsigned short* __restrict__ Qg, const unsigned short* __restrict__ Kg,
    const unsigned short* __restrict__ Vtg,
    unsigned short* __restrict__ outHi, unsigned short* __restrict__ outLo)
{
    const int id  = blockIdx.x;
    const int nid = (id & 7) * 384 + (id >> 3);
    const int bh  = nid / QT_PER, qt = nid % QT_PER;
    const int b   = bh >> 4, h = bh & 15;

    const int tid = threadIdx.x, lane = tid & 63, w = tid >> 6;
    const int g = lane >> 4, q16 = lane & 15;

    __shared__ __align__(16) unsigned short Ks[64][104];
    __shared__ __align__(16) unsigned short Vts[96][64];
    __shared__ __align__(16) unsigned short Ps[4][16][64];

    const int qrow = qt * 64 + w * 16 + q16;
    const unsigned short* qptr = Qg + ((size_t)bh * SPAD + qrow) * DPAD;
    bf16x8 qf[3];
#pragma unroll
    for (int c = 0; c < 3; ++c)
        qf[c] = *reinterpret_cast<const bf16x8*>(qptr + c * 32 + g * 8);

    f32x4 oacc[5];
#pragma unroll
    for (int dt = 0; dt < 5; ++dt) oacc[dt] = (f32x4){0.f, 0.f, 0.f, 0.f};
    float m_run = -INFINITY, l_run = 0.f;

    for (int j = 0; j < 12; ++j) {
        const int kbase = j * 64;
        for (int i = tid; i < 768; i += 256) {
            int r = i / 12, c = i % 12;
            uint4 v = *reinterpret_cast<const uint4*>(
                Kg + ((size_t)bh * SPAD + kbase + r) * DPAD + c * 8);
            *reinterpret_cast<uint4*>(&Ks[r][c * 8]) = v;
        }
        for (int i = tid; i < 768; i += 256) {
            int d = i >> 3, c = i & 7;
            uint4 v = *reinterpret_cast<const uint4*>(
                Vtg + ((size_t)bh * DPAD + d) * SPAD + kbase + c * 8);
            *reinterpret_cast<uint4*>(&Vts[d][(c ^ (d & 7)) * 8]) = v;
        }
        __syncthreads();

        f32x4 st[4];
#pragma unroll
        for (int t = 0; t < 4; ++t) {
            st[t] = (f32x4){0.f, 0.f, 0.f, 0.f};
#pragma unroll
            for (int c = 0; c < 3; ++c) {
                bf16x8 kf = *reinterpret_cast<const bf16x8*>(
                    &Ks[t * 16 + q16][c * 32 + g * 8]);
                st[t] = __builtin_amdgcn_mfma_f32_16x16x32_bf16(kf, qf[c], st[t], 0, 0, 0);
            }
        }
        if (j == 11) {
#pragma unroll
            for (int t = 0; t < 4; ++t)
#pragma unroll
                for (int r = 0; r < 4; ++r)
                    if (kbase + t * 16 + g * 4 + r >= S_LEN) st[t][r] = -1e30f;
        }

        float pm = -INFINITY;
#pragma unroll
        for (int t = 0; t < 4; ++t)
#pragma unroll
            for (int r = 0; r < 4; ++r) pm = fmaxf(pm, st[t][r]);
        pm = fmaxf(pm, __shfl_xor(pm, 16));
        pm = fmaxf(pm, __shfl_xor(pm, 32));
        const float mnew = fmaxf(m_run, pm);
        const float corr = __expf(m_run - mnew);
        float p[4][4];
        float ls = 0.f;
#pragma unroll
        for (int t = 0; t < 4; ++t)
#pragma unroll
            for (int r = 0; r < 4; ++r) {
                p[t][r] = __expf(st[t][r] - mnew);
                ls += p[t][r];
            }
        ls += __shfl_xor(ls, 16);
        ls += __shfl_xor(ls, 32);
        l_run = l_run * corr + ls;
        m_run = mnew;
#pragma unroll
        for (int dt = 0; dt < 5; ++dt) oacc[dt] *= corr;

#pragma unroll
        for (int t = 0; t < 4; ++t) {
            uint2 up;
            up.x = f32_bf16(p[t][0]) | ((unsigned int)f32_bf16(p[t][1]) << 16);
            up.y = f32_bf16(p[t][2]) | ((unsigned int)f32_bf16(p[t][3]) << 16);
            int ch = (2 * t + (g >> 1)) ^ (q16 & 7);
            *reinterpret_cast<uint2*>(
                reinterpret_cast<char*>(&Ps[w][q16][0]) + ch * 16 + (g & 1) * 8) = up;
        }

#pragma unroll
        for (int kc = 0; kc < 2; ++kc) {
            const int k0 = kc * 32;
            int pch = ((k0 >> 3) + g) ^ (q16 & 7);
            bf16x8 pf = *reinterpret_cast<const bf16x8*>(
                reinterpret_cast<char*>(&Ps[w][q16][0]) + pch * 16);
#pragma unroll
            for (int dt = 0; dt < 5; ++dt) {
                const int drow = dt * 16 + q16;
                int vch = ((k0 >> 3) + g) ^ (drow & 7);
                bf16x8 vf = *reinterpret_cast<const bf16x8*>(&Vts[drow][vch * 8]);
                oacc[dt] = __builtin_amdgcn_mfma_f32_16x16x32_bf16(vf, pf, oacc[dt], 0, 0, 0);
            }
        }
        __syncthreads();
    }

    const int q_local = qt * 64 + w * 16 + q16;
    if (q_local < S_LEN) {
        const float inv = 1.f / l_run;
        const size_t mrow = (size_t)b * S_LEN + q_local;
#pragma unroll
        for (int dt = 0; dt < 5; ++dt) {
            const int d0 = dt * 16 + g * 4;
            if (d0 < DH) {
                unsigned short hh[4], ll[4];
#pragma unroll
                for (int r = 0; r < 4; ++r) {
                    float o = oacc[dt][r] * inv;
                    hh[r] = f32_bf16(o);
                    ll[r] = f32_bf16(o - bf16_f32(hh[r]));
                }
                uint2 oh, ol;
                oh.x = hh[0] | ((unsigned int)hh[1] << 16);
                oh.y = hh[2] | ((unsigned int)hh[3] << 16);
                ol.x = ll[0] | ((unsigned int)ll[1] << 16);
                ol.y = ll[2] | ((unsigned int)ll[3] << 16);
                const size_t off = mrow * EMB + h * DH + d0;
                *reinterpret_cast<uint2*>(outHi + off) = oh;
                *reinterpret_cast<uint2*>(outLo + off) = ol;
            }
        }
    }
}

// ---------------------------------------------------------------------------
extern "C" void kernel_launch(void* const* d_in, const int* in_sizes, int n_in,
                              void* d_out, int out_size, void* d_ws, size_t ws_size,
                              hipStream_t stream)
{
    const float* x  = (const float*)d_in[0];
    const float* wq = (const float*)d_in[1];
    const float* bq = (const float*)d_in[2];
    const float* wk = (const float*)d_in[3];
    const float* bk = (const float*)d_in[4];
    const float* wv = (const float*)d_in[5];
    const float* bv = (const float*)d_in[6];
    const float* wo = (const float*)d_in[7];
    const float* bo = (const float*)d_in[8];
    float* out = (float*)d_out;

    float* ws = (float*)d_ws;
    const size_t per     = (size_t)M_ROWS * EMB;          // 13,436,928 f32
    const size_t perPad  = (size_t)M_PAD  * EMB;          // 13,565,952 elems
    const size_t XB_F32  = perPad / 2;                    // bf16 -> f32 units
    const size_t QG_F32  = (size_t)256 * SPAD * DPAD / 2; // 9,437,184

    // layout: [qb][kb][vb][xb][Qg][wt...]; overlays in time order:
    //   Kg -> qb, Vtg -> kb, outHi/outLo -> vb + spill into xb (xb dead by then)
    float* qb = ws;
    float* kb = ws + per;
    float* vb = ws + 2 * per;
    unsigned short* xb = (unsigned short*)(ws + 3 * per);
    unsigned short* Qg = (unsigned short*)(ws + 3 * per + XB_F32);
    unsigned short* wt = (unsigned short*)(ws + 3 * per + XB_F32 + QG_F32);

    unsigned short* Kg    = (unsigned short*)qb;
    unsigned short* Vtg   = (unsigned short*)kb;
    unsigned short* outHi = (unsigned short*)vb;          // [M_PAD][EMB] bf16
    unsigned short* outLo = outHi + perPad;               // spills into xb region

    const size_t WSZ = (size_t)EMB * EMB;
    unsigned short* wtq  = wt;
    unsigned short* wtk  = wt + WSZ;
    unsigned short* wtv  = wt + 2 * WSZ;
    unsigned short* wohi = wt + 3 * WSZ;
    unsigned short* wolo = wt + 4 * WSZ;

    const int n8v = (int)(per / 8);        // 1,679,616
    const int n8t = (int)(perPad / 8);     // 1,695,744
    dim3 cvtg((n8t + 255) / 256);
    dim3 tg(36, 36);
    dim3 gg(92, 9);
    dim3 bb(256);

    // input conversions
    cvt_bf16_pad_kernel<<<cvtg, bb, 0, stream>>>(x, xb, n8v, n8t);
    tcvt_kernel<false><<<tg, bb, 0, stream>>>(wq, wtq, nullptr);
    tcvt_kernel<false><<<tg, bb, 0, stream>>>(wk, wtk, nullptr);
    tcvt_kernel<false><<<tg, bb, 0, stream>>>(wv, wtv, nullptr);
    tcvt_kernel<true><<<tg, bb, 0, stream>>>(wo, wohi, wolo);

    // QKV projections + repacks
    const int rq_blocks = (256 * SPAD * 12) / 256;
    mfma_gemm_kernel<<<gg, bb, 0, stream>>>(xb, wtq, bq, qb);
    repack_qk_kernel<<<dim3(rq_blocks), bb, 0, stream>>>(qb, Qg, SCALE);
    mfma_gemm_kernel<<<gg, bb, 0, stream>>>(xb, wtk, bk, kb);
    repack_qk_kernel<<<dim3(rq_blocks), bb, 0, stream>>>(kb, Kg, 1.0f);
    mfma_gemm_kernel<<<gg, bb, 0, stream>>>(xb, wtv, bv, vb);
    dim3 vg(256, 12);
    repack_vt_kernel<<<vg, bb, 0, stream>>>(vb, Vtg);

    // flash attention (writes hi/lo split; xb is dead from here on)
    mfma_attn_kernel<<<dim3(256 * QT_PER), bb, 0, stream>>>(Qg, Kg, Vtg, outHi, outLo);

    // fused 3-term out-projection
    mfma_gemm3_kernel<<<gg, bb, 0, stream>>>(outHi, outLo, wohi, wolo, bo, out);
}